// Round 1
// baseline (148.196 us; speedup 1.0000x reference)
//
#include <hip/hip_runtime.h>

// DeterministicEncoder: MLP encoder [M,2]->[M,64] + Laplace-kernel attention.
// Algorithmic rewrite: exp(-|k-q|) factorizes into exp(-q)exp(k) (k<q) and
// exp(q)exp(-k) (k>=q). Sort context by k, build exclusive prefix Lo and
// suffix Hi sums of exp(+/-k)*v, then out[n] = e^{-q}Lo[j_n] + e^{q}Hi[j_n].
// O(N*M*OUT) -> O(M^2 rank + (M+N)*OUT).
//
// Shapes fixed by harness: M = N = 8192, H = 16, OUT = 64.
// Workspace: v (2MB) + skey/perm/rank (96KB) + Lo/Hi (4.2MB) = 6.25 MB.

#define H    16
#define OUTD 64
#define KSEG 1024   // key segment per rank block

__global__ __launch_bounds__(256) void mlp_kernel(
    const float* __restrict__ xc, const float* __restrict__ yc,
    const float* __restrict__ W1, const float* __restrict__ b1,
    const float* __restrict__ W2, const float* __restrict__ b2,
    const float* __restrict__ W3, const float* __restrict__ b3,
    float* __restrict__ v, int M)
{
    __shared__ float sW1[2 * H], sb1[H], sW2[H * H], sb2[H], sW3[H * OUTD], sb3[OUTD];
    int t = threadIdx.x;
    for (int i = t; i < 2 * H; i += 256) sW1[i] = W1[i];
    for (int i = t; i < H; i += 256) { sb1[i] = b1[i]; sb2[i] = b2[i]; }
    for (int i = t; i < H * H; i += 256) sW2[i] = W2[i];
    for (int i = t; i < H * OUTD; i += 256) sW3[i] = W3[i];
    for (int i = t; i < OUTD; i += 256) sb3[i] = b3[i];
    __syncthreads();

    int m = blockIdx.x * 256 + t;
    if (m >= M) return;
    float x = xc[m], y = yc[m];

    float h1[H];
#pragma unroll
    for (int j = 0; j < H; j++) {
        float a = x * sW1[j] + y * sW1[H + j] + sb1[j];
        h1[j] = a > 0.f ? a : 0.f;
    }
    float h2[H];
#pragma unroll
    for (int j = 0; j < H; j++) {
        float a = sb2[j];
#pragma unroll
        for (int i = 0; i < H; i++) a += h1[i] * sW2[i * H + j];
        h2[j] = a > 0.f ? a : 0.f;
    }
    float acc[OUTD];
#pragma unroll
    for (int c = 0; c < OUTD; c++) acc[c] = sb3[c];
#pragma unroll
    for (int i = 0; i < H; i++) {
        float h = h2[i];
#pragma unroll
        for (int c = 0; c < OUTD; c++) acc[c] += h * sW3[i * OUTD + c];
    }
    float4* vp = (float4*)(v + (size_t)m * OUTD);
#pragma unroll
    for (int c = 0; c < OUTD / 4; c++)
        vp[c] = make_float4(acc[4 * c], acc[4 * c + 1], acc[4 * c + 2], acc[4 * c + 3]);
}

// rank[m] = #{j : key[j] < key[m] or (key[j]==key[m] and j<m)} -- strict total
// order => rank is a permutation even with duplicate keys.
// grid = (M/256 row-blocks, M/KSEG key-segments); partial counts via atomicAdd.
__global__ __launch_bounds__(256) void rank_kernel(
    const float* __restrict__ key, int* __restrict__ rank, int M)
{
    __shared__ float sk[KSEG];
    int t = threadIdx.x;
    int kbase = blockIdx.y * KSEG;
    for (int i = t; i < KSEG; i += 256) sk[i] = key[kbase + i];
    __syncthreads();

    int m = blockIdx.x * 256 + t;
    if (m >= M) return;
    float mk = key[m];
    int cnt = 0;
#pragma unroll 2
    for (int j = 0; j < KSEG; j += 4) {
        float4 k4 = *(const float4*)(sk + j);   // LDS broadcast (uniform addr)
        int g = kbase + j;
        cnt += (k4.x < mk || (k4.x == mk && (g + 0) < m)) ? 1 : 0;
        cnt += (k4.y < mk || (k4.y == mk && (g + 1) < m)) ? 1 : 0;
        cnt += (k4.z < mk || (k4.z == mk && (g + 2) < m)) ? 1 : 0;
        cnt += (k4.w < mk || (k4.w == mk && (g + 3) < m)) ? 1 : 0;
    }
    atomicAdd(&rank[m], cnt);
}

__global__ __launch_bounds__(256) void scatter_kernel(
    const float* __restrict__ key, const int* __restrict__ rank,
    float* __restrict__ skey, int* __restrict__ perm, int M)
{
    int m = blockIdx.x * 256 + threadIdx.x;
    if (m < M) { int r = rank[m]; skey[r] = key[m]; perm[r] = m; }
}

// 128 blocks: block c in [0,64) -> Lo channel c; block 64+c -> Hi channel c.
// Lo[j] = sum_{i<j} exp(s_i) v[perm(i)][c]        (exclusive prefix, Lo[0]=0)
// Hi[j] = sum_{i>=j} exp(-s_i) v[perm(i)][c]      (suffix, Hi[M]=0)
// Requires M == 256*32 (harness: M=8192).
__global__ __launch_bounds__(256) void scan_kernel(
    const float* __restrict__ skey, const int* __restrict__ perm,
    const float* __restrict__ v, float* __restrict__ Lo, float* __restrict__ Hi, int M)
{
    __shared__ float ssum[256];
    int t = threadIdx.x;
    int c = blockIdx.x & 63;
    bool isHi = blockIdx.x >= 64;
    int base = t * 32;

    float w[32];
    float S = 0.f;
#pragma unroll 4
    for (int r = 0; r < 32; r++) {
        int i = base + r;
        int pos = isHi ? (M - 1 - i) : i;      // Hi scans positions in reverse
        float s = skey[pos];
        float e = __expf(isHi ? -s : s);
        float wv = e * v[(size_t)perm[pos] * OUTD + c];
        w[r] = wv;
        S += wv;
    }

    // block-level inclusive scan of per-thread chunk sums (Hillis-Steele)
    ssum[t] = S;
    __syncthreads();
    for (int off = 1; off < 256; off <<= 1) {
        float a = (t >= off) ? ssum[t - off] : 0.f;
        __syncthreads();
        ssum[t] += a;
        __syncthreads();
    }
    float incl = ssum[t];
    float chunk_off = incl - S;   // exclusive offset for this chunk

    if (!isHi) {
        float run = chunk_off;
#pragma unroll 4
        for (int r = 0; r < 32; r++) {
            int i = base + r;
            Lo[(size_t)i * OUTD + c] = run;    // exclusive
            run += w[r];
        }
        if (t == 255) Lo[(size_t)M * OUTD + c] = run;  // total
    } else {
        float run = chunk_off;
#pragma unroll 4
        for (int r = 0; r < 32; r++) {
            int i = base + r;
            run += w[r];                        // inclusive in reversed order
            Hi[(size_t)(M - 1 - i) * OUTD + c] = run;
        }
        if (t == 0) Hi[(size_t)M * OUTD + c] = 0.f;
    }
}

// One wave (64 lanes) per target n: identical binary search across lanes
// (scalar-ish broadcast loads), then coalesced 256B Lo/Hi reads + out write.
__global__ __launch_bounds__(256) void query_kernel(
    const float* __restrict__ xt, const float* __restrict__ skey,
    const float* __restrict__ Lo, const float* __restrict__ Hi,
    float* __restrict__ out, int M, int N)
{
    int tid = blockIdx.x * 256 + threadIdx.x;
    if (tid >= N * OUTD) return;
    int n = tid >> 6;
    int c = tid & 63;
    float q = xt[n];

    // j = #{keys < q}; ties go to the Hi side (exp(0)=1 either way).
    int lo = 0, hi = M;
    while (lo < hi) {
        int mid = (lo + hi) >> 1;
        if (skey[mid] < q) lo = mid + 1; else hi = mid;
    }
    float emq = __expf(-q);
    float epq = __expf(q);
    out[tid] = emq * Lo[(size_t)lo * OUTD + c] + epq * Hi[(size_t)lo * OUTD + c];
}

extern "C" void kernel_launch(void* const* d_in, const int* in_sizes, int n_in,
                              void* d_out, int out_size, void* d_ws, size_t ws_size,
                              hipStream_t stream)
{
    const float* xc = (const float*)d_in[0];
    const float* yc = (const float*)d_in[1];
    const float* xt = (const float*)d_in[2];
    const float* W1 = (const float*)d_in[3];
    const float* b1 = (const float*)d_in[4];
    const float* W2 = (const float*)d_in[5];
    const float* b2 = (const float*)d_in[6];
    const float* W3 = (const float*)d_in[7];
    const float* b3 = (const float*)d_in[8];
    float* out = (float*)d_out;

    int M = in_sizes[0];
    int N = in_sizes[2];

    // workspace carve-up (all 256B-aligned given aligned d_ws)
    char* ws = (char*)d_ws;
    float* v    = (float*)ws;                                   // M*64 f32
    float* skey = (float*)(ws + (size_t)M * OUTD * 4);          // M f32
    int*   perm = (int*)  (ws + (size_t)M * OUTD * 4 + (size_t)M * 4);
    int*   rank = (int*)  (ws + (size_t)M * OUTD * 4 + (size_t)M * 8);
    float* Lo   = (float*)(ws + (size_t)M * OUTD * 4 + (size_t)M * 12);  // (M+1)*64
    float* Hi   = Lo + (size_t)(M + 1) * OUTD;                           // (M+1)*64

    hipMemsetAsync(rank, 0, (size_t)M * sizeof(int), stream);

    mlp_kernel<<<(M + 255) / 256, 256, 0, stream>>>(xc, yc, W1, b1, W2, b2, W3, b3, v, M);
    rank_kernel<<<dim3(M / 256, M / KSEG), 256, 0, stream>>>(xc, rank, M);
    scatter_kernel<<<M / 256, 256, 0, stream>>>(xc, rank, skey, perm, M);
    scan_kernel<<<128, 256, 0, stream>>>(skey, perm, v, Lo, Hi, M);
    query_kernel<<<(N * OUTD + 255) / 256, 256, 0, stream>>>(xt, skey, Lo, Hi, out, M, N);
}